// Round 9
// baseline (212.542 us; speedup 1.0000x reference)
//
#include <hip/hip_runtime.h>
#include <hip/hip_fp16.h>

constexpr int N = 50000;        // nodes
constexpr int D = 64;           // feature dim
constexpr int E = 1600000;      // edges
constexpr int NBUCK = (N + 255) / 256;   // 196 buckets of 256 nodes (dst>>8)
constexpr int CAP = 10240;               // bucket window capacity (E/NBUCK=8163, sigma~90)
constexpr int CPT = 16;                  // edges per thread in k_bucket
constexpr int BUCK_BLOCKS = (E + 256 * CPT - 1) / (256 * CPT);  // 391

// ---------------------------------------------------------------------------
// K0: init per-bucket window cursors (cursor[b] = b*CAP)
__global__ void k_init(int* __restrict__ cursor) {
    int t = threadIdx.x;
    if (t < NBUCK) cursor[t] = t * CAP;
}

// K1: privatized counting-sort scatter -> fixed-capacity bucket windows.
// packed = dst<<16 | src (both < 65536). Per-(block,bucket) chunks contiguous.
__global__ void k_bucket(const int* __restrict__ src, const int* __restrict__ dst,
                         int* __restrict__ cursor, unsigned* __restrict__ packed) {
    __shared__ int lh[NBUCK];
    __shared__ int lb[NBUCK];
    int tid = threadIdx.x;
    for (int i = tid; i < NBUCK; i += 256) lh[i] = 0;
    __syncthreads();
    int base_e = blockIdx.x * (256 * CPT);
    unsigned pk[CPT];
    int bn[CPT], rk[CPT];
#pragma unroll
    for (int i = 0; i < CPT; ++i) {
        int e = base_e + i * 256 + tid;
        if (e < E) {
            int d = dst[e];
            int s = src[e];
            bn[i] = d >> 8;
            pk[i] = ((unsigned)d << 16) | (unsigned)s;
            rk[i] = atomicAdd(&lh[bn[i]], 1);
        } else bn[i] = -1;
    }
    __syncthreads();
    for (int i = tid; i < NBUCK; i += 256) {
        int c = lh[i];
        lb[i] = c ? atomicAdd(&cursor[i], c) : 0;   // one global atomic per bucket/block
    }
    __syncthreads();
#pragma unroll
    for (int i = 0; i < CPT; ++i)
        if (bn[i] >= 0) packed[lb[bn[i]] + rk[i]] = pk[i];
}

// K2: one block (1024 thr) per bucket — LDS histogram + scan -> rowptr/rowend/
// norm, then scatter src (u16) into the bucket's contiguous CSR window.
__global__ void k_csr(const int* __restrict__ cursor, const unsigned* __restrict__ packed,
                      unsigned short* __restrict__ csr, int* __restrict__ rowptr,
                      int* __restrict__ rowend, float* __restrict__ norm) {
    __shared__ int cnt[256];
    __shared__ int sm[256];
    __shared__ int cur[256];
    int b = blockIdx.x, tid = threadIdx.x;
    if (tid < 256) cnt[tid] = 0;
    __syncthreads();
    int beg = b * CAP;
    int end = cursor[b];                    // beg + count_b after k_bucket
    for (int j = beg + tid; j < end; j += 1024)
        atomicAdd(&cnt[(packed[j] >> 16) & 0xFF], 1);
    __syncthreads();
    if (tid < 256) sm[tid] = cnt[tid];
    __syncthreads();
    for (int off = 1; off < 256; off <<= 1) {
        int v = 0;
        if (tid < 256 && tid >= off) v = sm[tid - off];
        __syncthreads();
        if (tid < 256) sm[tid] += v;
        __syncthreads();
    }
    if (tid < 256) {
        int excl = (tid == 0) ? 0 : sm[tid - 1];
        int node = b * 256 + tid;
        if (node < N) {
            rowptr[node] = beg + excl;
            rowend[node] = beg + sm[tid];
            norm[node] = cnt[tid] ? rsqrtf((float)cnt[tid]) : 0.0f;
        }
        cur[tid] = beg + excl;
    }
    __syncthreads();
    for (int j = beg + tid; j < end; j += 1024) {
        unsigned p = packed[j];
        int slot = atomicAdd(&cur[(p >> 16) & 0xFF], 1);
        csr[slot] = (unsigned short)(p & 0xFFFFu);
    }
}

// K3: h2[row][d] = (sum_k x[row][k] * W[k][d]) * norm[row], stored fp16
__global__ void k_gemm(const float* __restrict__ x, const float* __restrict__ W,
                       const float* __restrict__ norm, __half* __restrict__ h2) {
    __shared__ float Wl[64 * 64];
    __shared__ float xs[16][64];
    int tid = threadIdx.x;
    const float4* W4 = (const float4*)W;
    float4* Wl4 = (float4*)Wl;
    Wl4[tid] = W4[tid];
    int r = tid >> 6, d = tid & 63;
    int row = blockIdx.x * 16 + r;
    xs[r][d] = x[row * 64 + d];
    __syncthreads();
    float a = 0.0f;
#pragma unroll
    for (int k = 0; k < 64; ++k) a = fmaf(xs[r][k], Wl[k * 64 + d], a);
    h2[row * 64 + d] = __float2half(a * norm[row]);
}

// K4: fused aggregate + dst-norm + bias + softplus.
// One wave per node. Lane = (edge-slot g=lane>>3, feature-chunk c=lane&7);
// one dwordx4 load covers 8 full 128B rows per wave instruction. 8-float
// register accumulator per lane; shfl_xor(8/16/32) reduction over edge
// slots; lanes g==0 do norm+bias+softplus and store two float4s.
__global__ void k_aggregate(const int* __restrict__ rowptr, const int* __restrict__ rowend,
                            const unsigned short* __restrict__ csr,
                            const __half* __restrict__ h2, const float* __restrict__ norm,
                            const float* __restrict__ bias, float* __restrict__ out) {
    int node = blockIdx.x * 4 + (threadIdx.x >> 6);
    int lane = threadIdx.x & 63;
    int g = lane >> 3;             // edge slot 0..7
    int c = lane & 7;              // feature chunk (features c*8 .. c*8+7)
    const uint4* h2v = (const uint4*)h2;   // row stride = 8 uint4
    int beg = rowptr[node];
    int end = rowend[node];
    float acc[8];
#pragma unroll
    for (int k = 0; k < 8; ++k) acc[k] = 0.0f;
    int j = beg;
    for (; j + 15 < end; j += 16) {          // 16 edges per iteration, 2 loads in flight
        int s0 = csr[j + g];
        int s1 = csr[j + 8 + g];
        uint4 p0 = h2v[s0 * 8 + c];
        uint4 p1 = h2v[s1 * 8 + c];
        const __half2* q0 = (const __half2*)&p0;
        const __half2* q1 = (const __half2*)&p1;
#pragma unroll
        for (int t = 0; t < 4; ++t) {
            float2 f0 = __half22float2(q0[t]);
            float2 f1 = __half22float2(q1[t]);
            acc[2 * t]     += f0.x + f1.x;
            acc[2 * t + 1] += f0.y + f1.y;
        }
    }
    for (; j + 7 < end; j += 8) {            // 8-edge chunk
        int s = csr[j + g];
        uint4 p = h2v[s * 8 + c];
        const __half2* q = (const __half2*)&p;
#pragma unroll
        for (int t = 0; t < 4; ++t) {
            float2 f = __half22float2(q[t]);
            acc[2 * t]     += f.x;
            acc[2 * t + 1] += f.y;
        }
    }
    if (j < end) {                           // tail <8 edges, predicated
        bool act = (j + g) < end;
        int s = act ? csr[j + g] : csr[j];   // safe index for inactive slots
        uint4 p = h2v[s * 8 + c];
        float m = act ? 1.0f : 0.0f;
        const __half2* q = (const __half2*)&p;
#pragma unroll
        for (int t = 0; t < 4; ++t) {
            float2 f = __half22float2(q[t]);
            acc[2 * t]     = fmaf(m, f.x, acc[2 * t]);
            acc[2 * t + 1] = fmaf(m, f.y, acc[2 * t + 1]);
        }
    }
    // reduce over the 8 edge slots (stride 8, 16, 32)
#pragma unroll
    for (int k = 0; k < 8; ++k) {
        acc[k] += __shfl_xor(acc[k], 8, 64);
        acc[k] += __shfl_xor(acc[k], 16, 64);
        acc[k] += __shfl_xor(acc[k], 32, 64);
    }
    if (g == 0) {
        float nrm = norm[node];
        float4 b0 = ((const float4*)bias)[c * 2];
        float4 b1 = ((const float4*)bias)[c * 2 + 1];
        float v0 = acc[0] * nrm + b0.x;
        float v1 = acc[1] * nrm + b0.y;
        float v2 = acc[2] * nrm + b0.z;
        float v3 = acc[3] * nrm + b0.w;
        float v4 = acc[4] * nrm + b1.x;
        float v5 = acc[5] * nrm + b1.y;
        float v6 = acc[6] * nrm + b1.z;
        float v7 = acc[7] * nrm + b1.w;
        float4 o0, o1;
        o0.x = fmaxf(v0, 0.0f) + log1pf(expf(-fabsf(v0)));
        o0.y = fmaxf(v1, 0.0f) + log1pf(expf(-fabsf(v1)));
        o0.z = fmaxf(v2, 0.0f) + log1pf(expf(-fabsf(v2)));
        o0.w = fmaxf(v3, 0.0f) + log1pf(expf(-fabsf(v3)));
        o1.x = fmaxf(v4, 0.0f) + log1pf(expf(-fabsf(v4)));
        o1.y = fmaxf(v5, 0.0f) + log1pf(expf(-fabsf(v5)));
        o1.z = fmaxf(v6, 0.0f) + log1pf(expf(-fabsf(v6)));
        o1.w = fmaxf(v7, 0.0f) + log1pf(expf(-fabsf(v7)));
        ((float4*)out)[node * 16 + c * 2]     = o0;
        ((float4*)out)[node * 16 + c * 2 + 1] = o1;
    }
}

extern "C" void kernel_launch(void* const* d_in, const int* in_sizes, int n_in,
                              void* d_out, int out_size, void* d_ws, size_t ws_size,
                              hipStream_t stream) {
    // inputs: t(f32,1), x(f32,N*D), weight(f32,D*D), bias(f32,D), src(i32,E), dst(i32,E)
    const float* x    = (const float*)d_in[1];
    const float* W    = (const float*)d_in[2];
    const float* bias = (const float*)d_in[3];
    const int* src = (const int*)d_in[4];
    const int* dst = (const int*)d_in[5];
    float* out = (float*)d_out;

    // workspace layout (~19.3 MB; poisoned 0xAA every call — every buffer is
    // fully written before it is read)
    char* ws = (char*)d_ws;
    __half*         h2     = (__half*)(ws);                        // 6.4 MB
    unsigned*       packed = (unsigned*)(ws + 6400000);            // NBUCK*CAP*4 = 8.03 MB
    unsigned short* csr    = (unsigned short*)(ws + 14427136);     // NBUCK*CAP*2 = 4.01 MB
    int*            rowptr = (int*)(ws + 18440704);                // N*4
    int*            rowend = (int*)(ws + 18640704);                // N*4
    float*          norm   = (float*)(ws + 18840704);              // N*4
    int*            cursor = (int*)(ws + 19040704);                // NBUCK

    k_init     <<<1, 256, 0, stream>>>(cursor);
    k_bucket   <<<BUCK_BLOCKS, 256, 0, stream>>>(src, dst, cursor, packed);
    k_csr      <<<NBUCK, 1024, 0, stream>>>(cursor, packed, csr, rowptr, rowend, norm);
    k_gemm     <<<(N + 15) / 16, 1024, 0, stream>>>(x, W, norm, h2);
    k_aggregate<<<(N + 3) / 4, 256, 0, stream>>>(rowptr, rowend, csr, h2, norm, bias, out);
}